// Round 3
// baseline (76.772 us; speedup 1.0000x reference)
//
#include <hip/hip_runtime.h>
#include <math.h>

typedef unsigned short u16;
typedef unsigned int   u32;

using bf16x8 = __attribute__((ext_vector_type(8))) short;
using f32x4  = __attribute__((ext_vector_type(4))) float;

#define NB   64      // batch
#define NE   8       // experts
#define DIN  320
#define NP   196     // real patches per image
#define MPAD 256     // padded row stride per image (A buffer)
#define CK   768     // inner dim (C*P*P)
#define CN   768     // out features

#define BM 128
#define BN 128
#define BK 32        // LDS row = 64 bytes = 4 chunks of 16B
#define NKT (CK / BK)   // 24

#define WCONV_BLOCKS 2304   // 8*768*768 / (8*256)
#define PATCH_BLOCKS 4704   // 64*196*96 / 256

__device__ __forceinline__ u16 f2bf(float f) {
    u32 u = __builtin_bit_cast(u32, f);
    u += 0x7fffu + ((u >> 16) & 1u);
    return (u16)(u >> 16);
}

__device__ __forceinline__ void gload16(const void* g, void* l) {
    __builtin_amdgcn_global_load_lds(
        (const __attribute__((address_space(1))) void*)g,
        (__attribute__((address_space(3))) void*)l, 16, 0, 0);
}

// ---------------- fused prep: gate (block 0) + wconv + patchify ----------------
__global__ __launch_bounds__(256) void prep_kernel(
    const float* __restrict__ x,
    const float* __restrict__ g,
    const float* __restrict__ noise,
    const float* __restrict__ w_gate,
    const float* __restrict__ w_noise,
    const float* __restrict__ w_exp,
    int* __restrict__ eid,
    float* __restrict__ loss_out,
    u16* __restrict__ patches,
    u16* __restrict__ wb)
{
    __shared__ float sW[DIN][NE];
    __shared__ float sWn[DIN][NE];
    __shared__ float sNy[NB][NE];
    __shared__ float sProb[NB][NE];
    __shared__ int   sTop[NB];
    __shared__ float sImp[NE], sLoad[NE];

    int bid = blockIdx.x;
    const int t = threadIdx.x;

    if (bid == 0) {
        // ---- gating + loss: 256 threads x 2 (b,e) pairs ----
        for (int i = t; i < DIN * NE; i += 256) {
            sW[i / NE][i % NE]  = w_gate[i];
            sWn[i / NE][i % NE] = w_noise[i];
        }
        __syncthreads();
        float cls[2], sds[2], nys[2];
        #pragma unroll
        for (int pp = 0; pp < 2; ++pp) {
            int p = t + pp * 256;
            int b = p >> 3, e = p & 7;
            float cl = 0.f, nz = 0.f;
            const float* gr = g + b * DIN;
            #pragma unroll 4
            for (int i = 0; i < DIN; ++i) {
                float gv = gr[i];
                cl = fmaf(gv, sW[i][e], cl);
                nz = fmaf(gv, sWn[i][e], nz);
            }
            // jax.nn.softplus == max(x,0)+log1p(exp(-|x|))
            float sd = fmaxf(nz, 0.f) + log1pf(expf(-fabsf(nz))) + 0.01f;
            float ny = fmaf(noise[p], sd, cl);
            sNy[b][e] = ny;
            cls[pp] = cl; sds[pp] = sd; nys[pp] = ny;
        }
        __syncthreads();
        #pragma unroll
        for (int pp = 0; pp < 2; ++pp) {
            int p = t + pp * 256;
            int b = p >> 3, e = p & 7;
            float v1 = -1e30f, v2 = -1e30f; int i1 = 0;
            #pragma unroll
            for (int k2 = 0; k2 < NE; ++k2) {
                float v = sNy[b][k2];
                if (v > v1) { v2 = v1; v1 = v; i1 = k2; }
                else if (v > v2) { v2 = v; }
            }
            if (e == 0) { sTop[b] = i1; eid[b] = i1; }
            // is_in: noisy > 2nd-largest (thr_in=v2); else threshold = largest (v1)
            float thr = (nys[pp] > v2) ? v2 : v1;
            float z = (cls[pp] - thr) / sds[pp];
            sProb[b][e] = 0.5f * (1.0f + erff(z * 0.7071067811865476f));
        }
        __syncthreads();
        if (t < NE) {
            float imp = 0.f, ld = 0.f;
            for (int i = 0; i < NB; ++i) {
                imp += (sTop[i] == t) ? 1.0f : 0.0f;
                ld  += sProb[i][t];
            }
            sImp[t] = imp; sLoad[t] = ld;
        }
        __syncthreads();
        if (t == 0) {
            float mi = 0.f, ml = 0.f;
            for (int k2 = 0; k2 < NE; ++k2) { mi += sImp[k2]; ml += sLoad[k2]; }
            mi *= (1.0f / NE); ml *= (1.0f / NE);
            float vi = 0.f, vl = 0.f;
            for (int k2 = 0; k2 < NE; ++k2) {
                float d1 = sImp[k2] - mi;  vi += d1 * d1;
                float d2 = sLoad[k2] - ml; vl += d2 * d2;
            }
            vi *= (1.0f / (NE - 1)); vl *= (1.0f / (NE - 1));  // ddof=1
            loss_out[0] = (vi / (mi * mi + 1e-10f) + vl / (ml * ml + 1e-10f)) * 0.01f;
        }
        return;
    }
    bid -= 1;

    if (bid < WCONV_BLOCKS) {
        // ---- w_exp fp32 -> bf16 ----
        int idx = bid * 256 + t;
        const float* src = w_exp + (size_t)idx * 8;
        float4 f0 = *reinterpret_cast<const float4*>(src);
        float4 f1 = *reinterpret_cast<const float4*>(src + 4);
        uint4 o;
        o.x = (u32)f2bf(f0.x) | ((u32)f2bf(f0.y) << 16);
        o.y = (u32)f2bf(f0.z) | ((u32)f2bf(f0.w) << 16);
        o.z = (u32)f2bf(f1.x) | ((u32)f2bf(f1.y) << 16);
        o.w = (u32)f2bf(f1.z) | ((u32)f2bf(f1.w) << 16);
        *reinterpret_cast<uint4*>(wb + (size_t)idx * 8) = o;
        return;
    }
    bid -= WCONV_BLOCKS;

    // ---- patchify + bf16 (real rows only; pad rows [196,256) never written) ----
    int idx = bid * 256 + t;
    int i8   = idx % 96;
    int rest = idx / 96;
    int p    = rest % NP;
    int b    = rest / NP;
    u16* dst = patches + ((size_t)(b * MPAD + p)) * CK + i8 * 8;
    int gh = p / 14, gw = p % 14;
    int i0  = i8 * 8;
    int c   = i0 >> 8;
    int rem = i0 & 255;
    int ph  = rem >> 4;
    int pw0 = rem & 15;
    const float* src = x + (((size_t)(b * 3 + c) * 224 + gh * 16 + ph) * 224 + gw * 16 + pw0);
    float4 f0 = *reinterpret_cast<const float4*>(src);
    float4 f1 = *reinterpret_cast<const float4*>(src + 4);
    uint4 o;
    o.x = (u32)f2bf(f0.x) | ((u32)f2bf(f0.y) << 16);
    o.y = (u32)f2bf(f0.z) | ((u32)f2bf(f0.w) << 16);
    o.z = (u32)f2bf(f1.x) | ((u32)f2bf(f1.y) << 16);
    o.w = (u32)f2bf(f1.z) | ((u32)f2bf(f1.w) << 16);
    *reinterpret_cast<uint4*>(dst) = o;
}

// ---------------- expert-selected batched GEMM, 2-phase dbuf + counted vmcnt ----------------
// grid: 768 blocks -> (image b, m-tile, n-tile); 256 thr = 4 waves (2x2),
// wave tile 64x64. global_load_lds staging, both-sides chunk swizzle
// c' = c ^ ((row>>2)&3). Double-buffered LDS; prefetch tile kt+1 is issued
// before computing tile kt; s_waitcnt vmcnt(4) keeps the 4 prefetch loads in
// flight across the barrier (T3/T4 minimum 2-phase recipe).
__global__ __launch_bounds__(256) void gemm_kernel(
    const u16* __restrict__ patches,
    const u16* __restrict__ wb,
    const float* __restrict__ b_exp,
    const int* __restrict__ eid,
    float* __restrict__ out)
{
    __shared__ char smem[2][16384];   // per buffer: A 8KB | B 8KB

    const int id = blockIdx.x;
    // bijective XCD swizzle: 96 consecutive virtual blocks (=8 images) per XCD
    const int v  = (id & 7) * 96 + (id >> 3);
    const int b  = v / 12;
    const int rr = v % 12;
    const int m0 = (rr / 6) * BM;
    const int n0 = (rr % 6) * BN;
    const int e  = eid[b];

    const int t  = threadIdx.x;
    const int l  = t & 63;
    const int w  = t >> 6;
    const int wm = w >> 1;
    const int wn = w & 1;

    // staging: wave w part j -> LDS bytes w*2048 + j*1024 + l*16
    // -> row r = w*32 + j*16 + (l>>2), chunk c' = l&3
    // pre-swizzled global chunk cg = c' ^ ((r>>2)&3) = (l&3) ^ (l>>4)
    const int rs = (w << 5) + (l >> 2);
    const u32 cg = (u32)((l & 3) ^ (l >> 4));
    const u16* aSrc = patches + ((size_t)(b * MPAD) + m0 + rs) * CK + cg * 8;
    const u16* bSrc = wb + (size_t)e * CK * CN + (size_t)(n0 + rs) * CK + cg * 8;
    const u32 lOff = (u32)(w * 2048);
    char* smem0 = &smem[0][0];

    // fragment read offsets (same swizzle), within A / B region
    u32 aOff[4], bOff[4];
    #pragma unroll
    for (int fm = 0; fm < 4; ++fm) {
        int row = wm * 64 + fm * 16 + (l & 15);
        u32 c = (u32)(l >> 4) ^ (u32)((row >> 2) & 3);
        aOff[fm] = (u32)row * 64 + c * 16;
    }
    #pragma unroll
    for (int fn = 0; fn < 4; ++fn) {
        int row = wn * 64 + fn * 16 + (l & 15);
        u32 c = (u32)(l >> 4) ^ (u32)((row >> 2) & 3);
        bOff[fn] = (u32)row * 64 + c * 16;
    }

    f32x4 acc[4][4];
    #pragma unroll
    for (int fm = 0; fm < 4; ++fm)
        #pragma unroll
        for (int fn = 0; fn < 4; ++fn)
            acc[fm][fn] = (f32x4){0.f, 0.f, 0.f, 0.f};

    // prologue: stage tile 0 into buf 0
    gload16(aSrc,           smem0 + lOff);
    gload16(aSrc + 16 * CK, smem0 + lOff + 1024);
    gload16(bSrc,           smem0 + 8192 + lOff);
    gload16(bSrc + 16 * CK, smem0 + 8192 + lOff + 1024);
    aSrc += BK; bSrc += BK;

    for (int kt = 0; kt < NKT - 1; ++kt) {
        // issue prefetch of tile kt+1 into the other buffer
        char* sn = smem0 + (u32)(((kt + 1) & 1) * 16384);
        gload16(aSrc,           sn + lOff);
        gload16(aSrc + 16 * CK, sn + lOff + 1024);
        gload16(bSrc,           sn + 8192 + lOff);
        gload16(bSrc + 16 * CK, sn + 8192 + lOff + 1024);
        aSrc += BK; bSrc += BK;

        // wait only for tile kt's 4 loads (prefetch stays in flight)
        asm volatile("s_waitcnt vmcnt(4)" ::: "memory");
        __builtin_amdgcn_s_barrier();

        char* sc = smem0 + (u32)((kt & 1) * 16384);
        bf16x8 af[4], bfr[4];
        #pragma unroll
        for (int fm = 0; fm < 4; ++fm)
            af[fm] = *reinterpret_cast<const bf16x8*>(sc + aOff[fm]);
        #pragma unroll
        for (int fn = 0; fn < 4; ++fn)
            bfr[fn] = *reinterpret_cast<const bf16x8*>(sc + 8192 + bOff[fn]);

        #pragma unroll
        for (int fm = 0; fm < 4; ++fm)
            #pragma unroll
            for (int fn = 0; fn < 4; ++fn)
                acc[fm][fn] = __builtin_amdgcn_mfma_f32_16x16x32_bf16(
                    af[fm], bfr[fn], acc[fm][fn], 0, 0, 0);

        __builtin_amdgcn_s_barrier();   // reads done before buffer reuse
    }

    // epilogue tile NKT-1 (in buf 1)
    asm volatile("s_waitcnt vmcnt(0)" ::: "memory");
    __builtin_amdgcn_s_barrier();
    {
        char* sc = smem0 + (u32)(((NKT - 1) & 1) * 16384);
        bf16x8 af[4], bfr[4];
        #pragma unroll
        for (int fm = 0; fm < 4; ++fm)
            af[fm] = *reinterpret_cast<const bf16x8*>(sc + aOff[fm]);
        #pragma unroll
        for (int fn = 0; fn < 4; ++fn)
            bfr[fn] = *reinterpret_cast<const bf16x8*>(sc + 8192 + bOff[fn]);
        #pragma unroll
        for (int fm = 0; fm < 4; ++fm)
            #pragma unroll
            for (int fn = 0; fn < 4; ++fn)
                acc[fm][fn] = __builtin_amdgcn_mfma_f32_16x16x32_bf16(
                    af[fm], bfr[fn], acc[fm][fn], 0, 0, 0);
    }

    // ---- store: bias + eps-replace, rows < 196 only ----
    const int r4 = (l >> 4) * 4;
    #pragma unroll
    for (int fm = 0; fm < 4; ++fm) {
        int mb = m0 + wm * 64 + fm * 16 + r4;
        #pragma unroll
        for (int fn = 0; fn < 4; ++fn) {
            int col = n0 + wn * 64 + fn * 16 + (l & 15);
            float bias = b_exp[e * CN + col];
            #pragma unroll
            for (int q = 0; q < 4; ++q) {
                int mrow = mb + q;
                if (mrow < NP) {
                    float vv = acc[fm][fn][q] + bias;
                    if (vv == 0.0f) vv = 2.220446049250313e-16f;
                    out[((size_t)b * NP + mrow) * CN + col] = vv;
                }
            }
        }
    }
}

extern "C" void kernel_launch(void* const* d_in, const int* in_sizes, int n_in,
                              void* d_out, int out_size, void* d_ws, size_t ws_size,
                              hipStream_t stream) {
    const float* x       = (const float*)d_in[0];
    const float* g       = (const float*)d_in[1];
    const float* noise   = (const float*)d_in[2];
    const float* w_gate  = (const float*)d_in[3];
    const float* w_noise = (const float*)d_in[4];
    const float* w_exp   = (const float*)d_in[5];
    const float* b_exp   = (const float*)d_in[6];
    float* out = (float*)d_out;

    char* ws = (char*)d_ws;
    int* eid      = (int*)ws;                                        // 256 B
    u16* patches  = (u16*)(ws + 1024);                               // 64*256*768*2
    u16* wbf      = (u16*)(ws + 1024 + (size_t)NB * MPAD * CK * 2);  // 8*768*768*2

    hipLaunchKernelGGL(prep_kernel, dim3(1 + WCONV_BLOCKS + PATCH_BLOCKS), dim3(256), 0, stream,
                       x, g, noise, w_gate, w_noise, w_exp,
                       eid, out + (size_t)NB * NP * CN, patches, wbf);
    hipLaunchKernelGGL(gemm_kernel, dim3(CN / BN * MPAD / BM * NB), dim3(256), 0, stream,
                       patches, wbf, b_exp, eid, out);
}